// Round 11
// baseline (469.264 us; speedup 1.0000x reference)
//
#include <hip/hip_runtime.h>

#define PI_F 3.14159265358979f

typedef _Float16 f16;
typedef _Float16 f16x8 __attribute__((ext_vector_type(8)));
typedef float f32x4 __attribute__((ext_vector_type(4)));

#define MFMA16(A,B,C) __builtin_amdgcn_mfma_f32_16x16x32_f16(A,B,C,0,0,0)

// ---- d_ws layout ----
// f16 region:
//   W0P [48][32]   @0      k:0..5 W0hi | 6..11 W0lo | 12..17 W0hi | 18 b0hi | 19 b0lo
//   W1P [80][64]   @1536   k<40 W1[k][n] | 40 b1hi | 41 b1lo | else 0
//   W2P [4][48][64]@6656   per g: k<40 W2[(40h+k)][40g+n] | 40/41 b2 hi/lo | else 0
//   W3P [4][80][64]@18944  per g: k<40 W3[(40g+k)][80g+n] | 40/41 b3 hi/lo | else 0
// float region @byte 78848: agw[512] (a*g*w per boundary pt) | fw[512] (f*w per interior pt)

__global__ __launch_bounds__(256)
void pack_kernel(const float* __restrict__ W0, const float* __restrict__ b0,
                 const float* __restrict__ W1, const float* __restrict__ b1,
                 const float* __restrict__ W2, const float* __restrict__ b2,
                 const float* __restrict__ W3, const float* __restrict__ b3,
                 const float* __restrict__ xb_coord, const float* __restrict__ xb_wts,
                 const int* __restrict__ xb_btype,
                 const float* __restrict__ xi_coord, const float* __restrict__ xi_wts,
                 const int* __restrict__ case_index,
                 f16* __restrict__ wp, float* __restrict__ fp)
{
  const int idx = blockIdx.x*256 + threadIdx.x;
  if (idx < 1536) {                       // W0P
    const int n = idx >> 5, k = idx & 31;
    float v = 0.f;
    if (n < 40) {
      if (k < 6) v = W0[k*40+n];
      else if (k < 12) { const float w = W0[(k-6)*40+n]; v = w - (float)(f16)w; }
      else if (k < 18) v = W0[(k-12)*40+n];
      else if (k == 18) v = b0[n];
      else if (k == 19) { const float w = b0[n]; v = w - (float)(f16)w; }
    }
    wp[idx] = (f16)v;
  } else if (idx < 6656) {                // W1P
    const int r = idx - 1536, n = r >> 6, k = r & 63;
    float v = 0.f;
    if (k < 40) v = W1[k*80+n];
    else if (k == 40) v = b1[n];
    else if (k == 41) { const float w = b1[n]; v = w - (float)(f16)w; }
    wp[idx] = (f16)v;
  } else if (idx < 18944) {               // W2P
    const int r = idx - 6656, g = r / 3072, q = r - g*3072, n = q >> 6, k = q & 63;
    float v = 0.f;
    if (n < 40) {
      if (k < 40) v = W2[(40*(g>>1)+k)*160 + 40*g + n];
      else if (k == 40) v = b2[40*g+n];
      else if (k == 41) { const float w = b2[40*g+n]; v = w - (float)(f16)w; }
    }
    wp[idx] = (f16)v;
  } else if (idx < 39424) {               // W3P
    const int r = idx - 18944, g = r / 5120, q = r - g*5120, n = q >> 6, k = q & 63;
    float v = 0.f;
    if (k < 40) v = W3[(40*g+k)*320 + 80*g + n];
    else if (k == 40) v = b3[80*g+n];
    else if (k == 41) { const float w = b3[80*g+n]; v = w - (float)(f16)w; }
    wp[idx] = (f16)v;
  } else if (idx < 39936) {               // agw
    const int p = idx - 39424;
    const float c = (float)(case_index[0]+1);
    const float x0=xb_coord[p*3], x1=xb_coord[p*3+1], x2=xb_coord[p*3+2];
    fp[p] = __sinf(c*(x0+x1+x2)) * (1.f + 0.1f*(float)xb_btype[p])
          * (1.f + 0.5f*__cosf(x0)) * xb_wts[p];
  } else if (idx < 40448) {               // fw
    const int p = idx - 39936;
    const float c = (float)(case_index[0]+1);
    fp[512+p] = __sinf(PI_F*c*xi_coord[p*3]) * __sinf(PI_F*xi_coord[p*3+1])
              * __sinf(PI_F*xi_coord[p*3+2]) * xi_wts[p];
  }
}

// Merged boundary+interior MFMA kernel. bid<2048: boundary (bid>>2 = z, 4
// panels of 16 JVP row-pairs); bid>=2048: interior. Each wave owns private
// 16-row activation panels in LDS (zero-init pads so A-garbage x B-zero = 0).
// Boundary rows interleave (value,dual) JVP pairs: in the MFMA C layout
// (col=lane&15, row=(lane>>4)*4+reg) a pair sits in the same lane at adjacent
// regs -> sin/cos*t combine is register-local, no shuffle.
// launch_bounds(...,3): cap VGPR ~170 -> 3 waves/SIMD; g-loops rolled to fit.
__global__ __launch_bounds__(256, 3)
void net_mfma(const float* __restrict__ xb_coord, const float* __restrict__ xb_normal,
              const float* __restrict__ xi_coord, const float* __restrict__ z_coord,
              const float* __restrict__ W4, const float* __restrict__ b4,
              const f16* __restrict__ wp, const float* __restrict__ fp,
              float* __restrict__ out)
{
  __shared__ f16 sm[4*6528];
  const int tid = threadIdx.x, lane = tid & 63;
  const int wv = __builtin_amdgcn_readfirstlane(tid >> 6);
  f16* XW = sm + wv*6528;
  f16* X0 = XW;            // [16][72]  data 0..39, fv 40,41
  f16* X1 = XW + 1152;     // [16][120] windows 48h: data 40, fv +40,+41
  f16* X2 = XW + 3072;     // [16][216] windows 48g: data 40, fv +40,+41
  const int r16 = lane & 15, quad = lane >> 4;

  const int bid = blockIdx.x;
  const bool bnd = (bid < 2048);
  int z, pbeg;
  const float* coord;
  if (bnd) { z = bid >> 2; pbeg = (bid & 3) * 4; coord = xb_coord; }
  else { const int b = bid - 2048; z = b >> 1; pbeg = (b & 1) * 4; coord = xi_coord; }
  const int pend = pbeg + 4;

  const float zc0 = z_coord[z*3+0], zc1 = z_coord[z*3+1], zc2 = z_coord[z*3+2];
  const f16* W0P = wp;
  const f16* W1P = wp + 1536;
  const f16* W2P = wp + 6656;
  const f16* W3P = wp + 18944;
  const float* FAC = bnd ? fp : (fp + 512);
  const float b4v = b4[0];
  const f32x4 czero = {0.f,0.f,0.f,0.f};

  // ---- init: zero wave-private LDS, then panel-invariant fv columns ----
  {
    f16x8 zz = {(f16)0.f,(f16)0.f,(f16)0.f,(f16)0.f,(f16)0.f,(f16)0.f,(f16)0.f,(f16)0.f};
    for (int i = lane; i < 816; i += 64) ((f16x8*)XW)[i] = zz;
    if (quad == 0) {
      const f16 fv = (f16)((bnd && (r16 & 1)) ? 0.f : 1.f);
      X0[r16*72 + 40] = fv;  X0[r16*72 + 41] = fv;
      X1[r16*120 + 40] = fv; X1[r16*120 + 41] = fv;
      X1[r16*120 + 88] = fv; X1[r16*120 + 89] = fv;
      #pragma unroll
      for (int g = 0; g < 4; g++) {
        X2[r16*216 + 48*g + 40] = fv; X2[r16*216 + 48*g + 41] = fv;
      }
    }
  }

  float wacc = 0.f;

  for (int panel = pbeg; panel < pend; panel++) {
    const int rowbase = panel*64 + wv*16;

    // ======== L0: split-f16 A (fp32-exact), B = W0P, 3 N-tiles ========
    {
      float i0,i1,i2,i3,i4,i5,fv;
      if (bnd) {
        const int r = rowbase + r16;
        const int p = r >> 1;
        if (r & 1) { i0=xb_normal[p*3]; i1=xb_normal[p*3+1]; i2=xb_normal[p*3+2];
                     i3=0.f;i4=0.f;i5=0.f; fv=0.f; }
        else       { i0=coord[p*3]; i1=coord[p*3+1]; i2=coord[p*3+2];
                     i3=zc0;i4=zc1;i5=zc2; fv=1.f; }
      } else {
        const int p = rowbase + r16;
        i0=coord[p*3]; i1=coord[p*3+1]; i2=coord[p*3+2]; i3=zc0;i4=zc1;i5=zc2; fv=1.f;
      }
      const f16 H0=(f16)i0,H1=(f16)i1,H2=(f16)i2,H3=(f16)i3,H4=(f16)i4,H5=(f16)i5;
      const f16 L0_=(f16)(i0-(float)H0), L1_=(f16)(i1-(float)H1), L2_=(f16)(i2-(float)H2);
      const f16 L3_=(f16)(i3-(float)H3), L4_=(f16)(i4-(float)H4), L5_=(f16)(i5-(float)H5);
      const f16 FV=(f16)fv, Z=(f16)0.f;
      f16x8 a = {Z,Z,Z,Z,Z,Z,Z,Z};
      if (quad == 0)      { a[0]=H0;a[1]=H1;a[2]=H2;a[3]=H3;a[4]=H4;a[5]=H5;a[6]=H0;a[7]=H1; }
      else if (quad == 1) { a[0]=H2;a[1]=H3;a[2]=H4;a[3]=H5;a[4]=L0_;a[5]=L1_;a[6]=L2_;a[7]=L3_; }
      else if (quad == 2) { a[0]=L4_;a[1]=L5_;a[2]=FV;a[3]=FV; }

      #pragma unroll
      for (int t = 0; t < 3; t++) {
        const f16x8 b = *(const f16x8*)(W0P + (t*16 + r16)*32 + quad*8);
        const f32x4 c = MFMA16(a, b, czero);
        const int col = t*16 + r16;
        if (t < 2 || r16 < 8) {
          if (bnd) {
            float s0, c0v, s2, c2v;
            __sincosf(c[0], &s0, &c0v);
            __sincosf(c[2], &s2, &c2v);
            X0[(quad*4+0)*72 + col] = (f16)s0;
            X0[(quad*4+1)*72 + col] = (f16)(c0v * c[1]);
            X0[(quad*4+2)*72 + col] = (f16)s2;
            X0[(quad*4+3)*72 + col] = (f16)(c2v * c[3]);
          } else {
            X0[(quad*4+0)*72 + col] = (f16)__sinf(c[0]);
            X0[(quad*4+1)*72 + col] = (f16)__sinf(c[1]);
            X0[(quad*4+2)*72 + col] = (f16)__sinf(c[2]);
            X0[(quad*4+3)*72 + col] = (f16)__sinf(c[3]);
          }
        }
      }
    }

    // ======== L1: X0 -> X1 (K=64 in 2 chunks; N=80, 5 tiles) ========
    {
      const f16x8 A0 = *(const f16x8*)(X0 + r16*72 + quad*8);
      const f16x8 A1 = *(const f16x8*)(X0 + r16*72 + 32 + quad*8);
      #pragma unroll 2
      for (int t = 0; t < 5; t++) {
        const f16* bp = W1P + (t*16 + r16)*64 + quad*8;
        const f16x8 b0 = *(const f16x8*)bp;
        const f16x8 b1 = *(const f16x8*)(bp + 32);
        f32x4 c = MFMA16(A0, b0, czero);
        c = MFMA16(A1, b1, c);
        const int n = t*16 + r16;
        const int col = n + (n >= 40 ? 8 : 0);
        if (bnd) {
          float s0, c0v, s2, c2v;
          __sincosf(c[0], &s0, &c0v);
          __sincosf(c[2], &s2, &c2v);
          X1[(quad*4+0)*120 + col] = (f16)s0;
          X1[(quad*4+1)*120 + col] = (f16)(c0v * c[1]);
          X1[(quad*4+2)*120 + col] = (f16)s2;
          X1[(quad*4+3)*120 + col] = (f16)(c2v * c[3]);
        } else {
          X1[(quad*4+0)*120 + col] = (f16)__sinf(c[0]);
          X1[(quad*4+1)*120 + col] = (f16)__sinf(c[1]);
          X1[(quad*4+2)*120 + col] = (f16)__sinf(c[2]);
          X1[(quad*4+3)*120 + col] = (f16)__sinf(c[3]);
        }
      }
    }

    // ======== L2: X1 -> X2, per branch g (window 48h; N=40 -> 3 tiles) ========
    #pragma unroll 1
    for (int g = 0; g < 4; g++) {
      const int h = g >> 1;
      const f16x8 A0 = *(const f16x8*)(X1 + r16*120 + 48*h + quad*8);
      const f16x8 A1 = *(const f16x8*)(X1 + r16*120 + 48*h + 32 + quad*8);
      #pragma unroll 2
      for (int t = 0; t < 3; t++) {
        const f16* bp = W2P + g*3072 + (t*16 + r16)*64 + quad*8;
        const f16x8 b0 = *(const f16x8*)bp;
        const f16x8 b1 = *(const f16x8*)(bp + 32);
        f32x4 c = MFMA16(A0, b0, czero);
        c = MFMA16(A1, b1, c);
        if (t < 2 || r16 < 8) {
          const int col = 48*g + t*16 + r16;
          if (bnd) {
            float s0, c0v, s2, c2v;
            __sincosf(c[0], &s0, &c0v);
            __sincosf(c[2], &s2, &c2v);
            X2[(quad*4+0)*216 + col] = (f16)s0;
            X2[(quad*4+1)*216 + col] = (f16)(c0v * c[1]);
            X2[(quad*4+2)*216 + col] = (f16)s2;
            X2[(quad*4+3)*216 + col] = (f16)(c2v * c[3]);
          } else {
            X2[(quad*4+0)*216 + col] = (f16)__sinf(c[0]);
            X2[(quad*4+1)*216 + col] = (f16)__sinf(c[1]);
            X2[(quad*4+2)*216 + col] = (f16)__sinf(c[2]);
            X2[(quad*4+3)*216 + col] = (f16)__sinf(c[3]);
          }
        }
      }
    }

    // ======== L3 + fused W4 dot, per branch g (window 48g; N=80, 5 tiles) ========
    float p0=0.f, p1=0.f, p2=0.f, p3=0.f;
    #pragma unroll 1
    for (int g = 0; g < 4; g++) {
      const f16x8 A0 = *(const f16x8*)(X2 + r16*216 + 48*g + quad*8);
      const f16x8 A1 = *(const f16x8*)(X2 + r16*216 + 48*g + 32 + quad*8);
      #pragma unroll 2
      for (int t = 0; t < 5; t++) {
        const f16* bp = W3P + g*5120 + (t*16 + r16)*64 + quad*8;
        const f16x8 b0 = *(const f16x8*)bp;
        const f16x8 b1 = *(const f16x8*)(bp + 32);
        f32x4 c = MFMA16(A0, b0, czero);
        c = MFMA16(A1, b1, c);
        const float w4 = W4[80*g + t*16 + r16];
        if (bnd) {
          p1 += __cosf(c[0]) * c[1] * w4;   // dual rows only (Gn)
          p3 += __cosf(c[2]) * c[3] * w4;
        } else {
          p0 += __sinf(c[0]) * w4;
          p1 += __sinf(c[1]) * w4;
          p2 += __sinf(c[2]) * w4;
          p3 += __sinf(c[3]) * w4;
        }
      }
    }

    // reduce row-sums across the 16 col-lanes (quad preserved)
    #pragma unroll
    for (int m = 1; m < 16; m <<= 1) {
      p1 += __shfl_xor(p1, m);
      p3 += __shfl_xor(p3, m);
      if (!bnd) { p0 += __shfl_xor(p0, m); p2 += __shfl_xor(p2, m); }
    }
    if (r16 == 0) {
      if (bnd) {
        const int pr = (rowbase >> 1) + quad*2;   // pair index of rows quad*4+1, +3
        wacc += p1 * FAC[pr] + p3 * FAC[pr+1];
      } else {
        const int r0 = rowbase + quad*4;
        wacc += (p0+b4v)*FAC[r0] + (p1+b4v)*FAC[r0+1]
              + (p2+b4v)*FAC[r0+2] + (p3+b4v)*FAC[r0+3];
      }
    }
  }

  #pragma unroll
  for (int m = 16; m < 64; m <<= 1) wacc += __shfl_xor(wacc, m);
  if (lane == 0) atomicAdd(out + z, bnd ? -wacc : wacc);
}

extern "C" void kernel_launch(void* const* d_in, const int* in_sizes, int n_in,
                              void* d_out, int out_size, void* d_ws, size_t ws_size,
                              hipStream_t stream) {
  const float* xi_coord  = (const float*)d_in[0];
  const float* xi_wts    = (const float*)d_in[1];
  const float* xb_coord  = (const float*)d_in[2];
  const float* xb_wts    = (const float*)d_in[3];
  const float* xb_normal = (const float*)d_in[4];
  const float* z_coord   = (const float*)d_in[5];
  const float* W0 = (const float*)d_in[6];
  const float* b0 = (const float*)d_in[7];
  const float* W1 = (const float*)d_in[8];
  const float* b1 = (const float*)d_in[9];
  const float* W2 = (const float*)d_in[10];
  const float* b2 = (const float*)d_in[11];
  const float* W3 = (const float*)d_in[12];
  const float* b3 = (const float*)d_in[13];
  const float* W4 = (const float*)d_in[14];
  const float* b4 = (const float*)d_in[15];
  const int* xb_btype   = (const int*)d_in[16];
  const int* case_index = (const int*)d_in[17];
  float* out = (float*)d_out;
  f16* wp = (f16*)d_ws;                              // 39424 f16 = 78848 B
  float* fpf = (float*)((char*)d_ws + 78848);        // agw[512] | fw[512]

  hipMemsetAsync(d_out, 0, (size_t)out_size * sizeof(float), stream);

  hipLaunchKernelGGL(pack_kernel, dim3(158), dim3(256), 0, stream,
      W0, b0, W1, b1, W2, b2, W3, b3,
      xb_coord, xb_wts, xb_btype, xi_coord, xi_wts, case_index, wp, fpf);

  // 2048 boundary blocks + 1024 interior blocks, 4 panels each
  hipLaunchKernelGGL(net_mfma, dim3(3072), dim3(256), 0, stream,
      xb_coord, xb_normal, xi_coord, z_coord, W4, b4, wp, fpf, out);
}